// Round 8
// baseline (434.423 us; speedup 1.0000x reference)
//
#include <hip/hip_runtime.h>
#include <math.h>

#define DD 128
#define HH 32
#define MH 64
#define TT 256
#define ETA_C 1e-3f
#define BOUND_C 1.4907119849998598f   // sqrt(2/0.9)

// ws float layout:
//   F[32][128] @ 0     fn2[32] @ 8192   s4[32] @ 8224   m0n2[32] @ 8256
//   P[32][128] @ 4096
//   X store @ 8320 (257*128)   U store @ 41216 (256*128)
#define WSX 8320
#define WSU 41216

typedef float v2f __attribute__((ext_vector_type(2)));

#define KEEPV(v) asm volatile("" : "+v"(v))

template <int CTRL>
__device__ __forceinline__ float dpp_add(float x) {
    int y = __builtin_amdgcn_update_dpp(0, __float_as_int(x), CTRL, 0xF, 0xF, true);
    return x + __int_as_float(y);
}
// 0xB1 quad xor1, 0x4E quad xor2, 0x104 row_shl:4 (lane i <- lane i+4),
// 0x124 row_ror:4, 0x128 row_ror:8

__global__ void k_precompF(const float* __restrict__ W, const float* __restrict__ phi,
                           const float* __restrict__ sigma, float* __restrict__ ws) {
    int i = blockIdx.x, d = threadIdx.x;
    float acc = 0.f;
#pragma unroll
    for (int m = 0; m < MH; ++m) acc += W[d * MH + m] * phi[m * HH + i];
    ws[i * DD + d] = acc;
    __shared__ float red[DD];
    red[d] = acc * acc;
    __syncthreads();
    for (int o = 64; o > 0; o >>= 1) {
        if (d < o) red[d] += red[d + o];
        __syncthreads();
    }
    if (d == 0) {
        ws[8192 + i] = red[0];
        ws[8224 + i] = sqrtf(sqrtf(sigma[i]));
    }
}

__global__ void k_precompP(const float* __restrict__ M0, float* __restrict__ ws) {
    int i = blockIdx.x, n = threadIdx.x;
    const float* f  = ws + i * DD;
    const float* m0 = M0 + i * DD * DD + n * DD;
    float p = 0.f, sq = 0.f;
#pragma unroll 4
    for (int d = 0; d < DD; ++d) {
        float v = m0[d];
        p  += v * f[d];
        sq += v * v;
    }
    ws[4096 + i * DD + n] = p;
    __shared__ float red[DD];
    red[n] = sq;
    __syncthreads();
    for (int o = 64; o > 0; o >>= 1) {
        if (n < o) red[n] += red[n + o];
        __syncthreads();
    }
    if (n == 0) ws[8256 + i] = red[0];
}

__launch_bounds__(1024, 4)
__global__ void k_scan(const float* __restrict__ Am, const float* __restrict__ Bm,
                       const float* __restrict__ Rm, const float* __restrict__ Km,
                       const float* __restrict__ x0, const float* __restrict__ wseq,
                       float* __restrict__ ws) {
    const int tid = threadIdx.x;
    const int r = tid >> 3, s = tid & 7;

    // Thread owns row r, cols {4s+32q+0..3}, q=0..3. 64 matrix VGPRs/thread.
    v2f mK[8], mA[8], mB[8], mR[8];
#pragma unroll
    for (int q = 0; q < 4; ++q) {
        const int col = 4 * s + 32 * q;
        float4 v;
        v = *(const float4*)(Km + r * DD + col);
        mK[2*q] = v2f{v.x, v.y}; mK[2*q+1] = v2f{v.z, v.w};
        v = *(const float4*)(Am + r * DD + col);
        mA[2*q] = v2f{v.x, v.y}; mA[2*q+1] = v2f{v.z, v.w};
        v = *(const float4*)(Bm + r * DD + col);
        mB[2*q] = v2f{v.x, v.y}; mB[2*q+1] = v2f{v.z, v.w};
        v = *(const float4*)(Rm + r * DD + col);
        v.x += Rm[(col + 0) * DD + r];   // Rsym = R + R^T
        v.y += Rm[(col + 1) * DD + r];
        v.z += Rm[(col + 2) * DD + r];
        v.w += Rm[(col + 3) * DD + r];
        mR[2*q] = v2f{v.x, v.y}; mR[2*q+1] = v2f{v.z, v.w};
    }
#pragma unroll
    for (int q = 0; q < 8; ++q) { KEEPV(mK[q]); KEEPV(mA[q]); KEEPV(mB[q]); KEEPV(mR[q]); }

    // Filter state (first 512 threads): filter oi = tid>>4, elems on0..on0+7.
    const int oi = tid >> 4, ol = tid & 15, on0 = ol << 3;
    float y[8], p[8];
    float oa = 1.f, ony2 = 0.f, oyp = 0.f;
    float os4 = 0.f, ofn2 = 0.f, om0 = 0.f, oe = 0.f;

    __shared__ float xs[2][DD];
    __shared__ float us[DD], gs[DD];
    __shared__ float Zl[HH * 131];   // odd stride: conflict-free z-fold reads

    if (tid < 512) {
        os4  = ws[8224 + oi];
        ofn2 = ws[8192 + oi];
        om0  = ws[8256 + oi];
        oe   = ETA_C * os4;
#pragma unroll
        for (int j = 0; j < 8; ++j) {
            y[j] = 0.f;
            p[j] = ws[4096 + oi * DD + on0 + j];
        }
#pragma unroll
        for (int j = 0; j < 8; ++j) Zl[oi * 131 + on0 + j] = os4 * p[j];
    }
    if (tid < DD) {
        float xv = x0[tid];
        xs[0][tid] = xv;
        ws[WSX + tid] = xv;
    }
    __syncthreads();

    float axr = 0.f;
#pragma unroll 1
    for (int t = 0; t < TT; ++t) {
        float* xcur = xs[t & 1];
        float* xnxt = xs[(t & 1) ^ 1];
        float wv = 0.f;
        if (s == 0) wv = wseq[t * DD + r];   // prefetch, consumed in phase B

        // ---- phase A: u[r] = noise[r] - (K x)[r]; (A x)[r] partial kept in reg
        {
            const float4* x4p = (const float4*)xcur;
            v2f aK = v2f{0.f, 0.f}, aA = v2f{0.f, 0.f};
#pragma unroll
            for (int q = 0; q < 4; ++q) {
                float4 xq = x4p[s + 8 * q];
                v2f lo = v2f{xq.x, xq.y}, hi = v2f{xq.z, xq.w};
                aK += mK[2*q] * lo; aK += mK[2*q+1] * hi;
                aA += mA[2*q] * lo; aA += mA[2*q+1] * hi;
            }
            float zp = 0.f;
#pragma unroll
            for (int j = 0; j < 4; ++j) zp += Zl[(4 * s + j) * 131 + r];
            float uval = zp - (aK.x + aK.y);
            float av = aA.x + aA.y;
            uval = dpp_add<0xB1>(uval); uval = dpp_add<0x4E>(uval); uval = dpp_add<0x104>(uval);
            av   = dpp_add<0xB1>(av);   av   = dpp_add<0x4E>(av);   av   = dpp_add<0x104>(av);
            if (s == 0) {
                us[r] = uval;
                ws[WSU + t * DD + r] = uval;   // for deferred cost kernel
            }
            axr = av;
        }
        asm volatile("s_waitcnt lgkmcnt(0)" ::: "memory");
        __builtin_amdgcn_s_barrier();

        // ---- phase B: g = Rsym u ; x_next = Ax + Bu + w
        {
            const float4* u4p = (const float4*)us;
            v2f aR = v2f{0.f, 0.f}, aB = v2f{0.f, 0.f};
#pragma unroll
            for (int q = 0; q < 4; ++q) {
                float4 uq = u4p[s + 8 * q];
                v2f lo = v2f{uq.x, uq.y}, hi = v2f{uq.z, uq.w};
                aR += mR[2*q] * lo; aR += mR[2*q+1] * hi;
                aB += mB[2*q] * lo; aB += mB[2*q+1] * hi;
            }
            float gv = aR.x + aR.y, bv = aB.x + aB.y;
            gv = dpp_add<0xB1>(gv); gv = dpp_add<0x4E>(gv); gv = dpp_add<0x104>(gv);
            bv = dpp_add<0xB1>(bv); bv = dpp_add<0x4E>(bv); bv = dpp_add<0x104>(bv);
            if (s == 0) {
                gs[r] = gv;
                float xn = axr + bv + wv;
                xnxt[r] = xn;
                ws[WSX + (t + 1) * DD + r] = xn;
            }
        }
        asm volatile("s_waitcnt lgkmcnt(0)" ::: "memory");
        __builtin_amdgcn_s_barrier();

        // ---- phase C: filter update with incremental norm tracking (tid<512)
        if (tid < 512) {
            const float4* g4 = (const float4*)(gs + on0);
            float4 ga = g4[0], gb = g4[1];
            float g8[8] = {ga.x, ga.y, ga.z, ga.w, gb.x, gb.y, gb.z, gb.w};
            float yg = 0.f, gp = 0.f, g2 = 0.f;
#pragma unroll
            for (int j = 0; j < 8; ++j) {
                yg += y[j] * g8[j];
                gp += p[j] * g8[j];
                g2 += g8[j] * g8[j];
            }
            yg = dpp_add<0xB1>(yg); yg = dpp_add<0x4E>(yg);
            yg = dpp_add<0x124>(yg); yg = dpp_add<0x128>(yg);
            gp = dpp_add<0xB1>(gp); gp = dpp_add<0x4E>(gp);
            gp = dpp_add<0x124>(gp); gp = dpp_add<0x128>(gp);
            g2 = dpp_add<0xB1>(g2); g2 = dpp_add<0x4E>(g2);
            g2 = dpp_add<0x124>(g2); g2 = dpp_add<0x128>(g2);
            float ny2 = ony2 - 2.f * oe * yg + oe * oe * g2;
            float yp  = oyp - oe * gp;
            float norm2 = oa * oa * om0 + 2.f * oa * yp + ofn2 * ny2;
            float nrm = sqrtf(fmaxf(norm2, 0.f));
            float sc = (nrm > BOUND_C) ? (BOUND_C / nrm) : 1.f;
            oa *= sc; ony2 = ny2 * sc * sc; oyp = yp * sc;
            float ca = os4 * oa, cy = os4 * ofn2;
#pragma unroll
            for (int j = 0; j < 8; ++j) {
                y[j] = sc * (y[j] - oe * g8[j]);
                Zl[oi * 131 + on0 + j] = ca * p[j] + cy * y[j];
            }
        }
        asm volatile("s_waitcnt lgkmcnt(0)" ::: "memory");
        __builtin_amdgcn_s_barrier();
    }
}

// Deferred, fully parallel cost: out[t] = x_t' Q x_t + u_t' R u_t
__launch_bounds__(128)
__global__ void k_cost(const float* __restrict__ Qm, const float* __restrict__ Rm,
                       const float* __restrict__ ws, float* __restrict__ out) {
    const int t = blockIdx.x, r = threadIdx.x;
    __shared__ float xv[DD], uv[DD];
    __shared__ float red[2];
    xv[r] = ws[WSX + t * DD + r];
    uv[r] = ws[WSU + t * DD + r];
    __syncthreads();
    const float4* q4 = (const float4*)(Qm + r * DD);
    const float4* r4 = (const float4*)(Rm + r * DD);
    const float4* x4 = (const float4*)xv;
    const float4* u4 = (const float4*)uv;
    float qa = 0.f, ra = 0.f;
#pragma unroll 8
    for (int j = 0; j < 32; ++j) {
        float4 qv = q4[j], xq = x4[j];
        qa += qv.x*xq.x + qv.y*xq.y + qv.z*xq.z + qv.w*xq.w;
        float4 rv = r4[j], uq = u4[j];
        ra += rv.x*uq.x + rv.y*uq.y + rv.z*uq.z + rv.w*uq.w;
    }
    float part = xv[r] * qa + uv[r] * ra;
    part = dpp_add<0xB1>(part); part = dpp_add<0x4E>(part);
    part = dpp_add<0x124>(part); part = dpp_add<0x128>(part);
    part += __shfl_xor(part, 16); part += __shfl_xor(part, 32);
    if ((r & 63) == 0) red[r >> 6] = part;
    __syncthreads();
    if (r == 0) out[t] = red[0] + red[1];
}

extern "C" void kernel_launch(void* const* d_in, const int* in_sizes, int n_in,
                              void* d_out, int out_size, void* d_ws, size_t ws_size,
                              hipStream_t stream) {
    const float* A     = (const float*)d_in[0];
    const float* B     = (const float*)d_in[1];
    const float* Q     = (const float*)d_in[2];
    const float* R     = (const float*)d_in[3];
    const float* K     = (const float*)d_in[4];
    const float* sigma = (const float*)d_in[5];
    const float* phi   = (const float*)d_in[6];
    const float* M0    = (const float*)d_in[7];
    const float* x0    = (const float*)d_in[8];
    const float* Whist = (const float*)d_in[9];
    const float* wseq  = (const float*)d_in[10];
    float* out = (float*)d_out;
    float* ws  = (float*)d_ws;

    hipLaunchKernelGGL(k_precompF, dim3(HH), dim3(DD), 0, stream, Whist, phi, sigma, ws);
    hipLaunchKernelGGL(k_precompP, dim3(HH), dim3(DD), 0, stream, M0, ws);
    hipLaunchKernelGGL(k_scan, dim3(1), dim3(1024), 0, stream,
                       A, B, R, K, x0, wseq, ws);
    hipLaunchKernelGGL(k_cost, dim3(TT), dim3(DD), 0, stream, Q, R, ws, out);
}

// Round 9
// 433.625 us; speedup vs baseline: 1.0018x; 1.0018x over previous
//
#include <hip/hip_runtime.h>
#include <math.h>

#define DD 128
#define HH 32
#define MH 64
#define TT 256
#define ETA_C 1e-3f
#define BOUND_C 1.4907119849998598f   // sqrt(2/0.9)

// ws float layout:
//   F[32][128] @ 0     fn2[32] @ 8192   s4[32] @ 8224   m0n2[32] @ 8256
//   P[32][128] @ 4096
//   X store @ 8320 (257*128)   U store @ 41216 (256*128)
#define WSX 8320
#define WSU 41216

typedef float v2f __attribute__((ext_vector_type(2)));

#define KEEPV(v) asm volatile("" : "+v"(v))

template <int CTRL>
__device__ __forceinline__ float dpp_add(float x) {
    int y = __builtin_amdgcn_update_dpp(0, __float_as_int(x), CTRL, 0xF, 0xF, true);
    return x + __int_as_float(y);
}
// 0xB1 quad xor1, 0x4E quad xor2, 0x104 row_shl:4 (lane i <- lane i+4),
// 0x124 row_ror:4, 0x128 row_ror:8

__global__ void k_precompF(const float* __restrict__ W, const float* __restrict__ phi,
                           const float* __restrict__ sigma, float* __restrict__ ws) {
    int i = blockIdx.x, d = threadIdx.x;
    float acc = 0.f;
#pragma unroll
    for (int m = 0; m < MH; ++m) acc += W[d * MH + m] * phi[m * HH + i];
    ws[i * DD + d] = acc;
    __shared__ float red[DD];
    red[d] = acc * acc;
    __syncthreads();
    for (int o = 64; o > 0; o >>= 1) {
        if (d < o) red[d] += red[d + o];
        __syncthreads();
    }
    if (d == 0) {
        ws[8192 + i] = red[0];
        ws[8224 + i] = sqrtf(sqrtf(sigma[i]));
    }
}

__global__ void k_precompP(const float* __restrict__ M0, float* __restrict__ ws) {
    int i = blockIdx.x, n = threadIdx.x;
    const float* f  = ws + i * DD;
    const float* m0 = M0 + i * DD * DD + n * DD;
    float p = 0.f, sq = 0.f;
#pragma unroll 4
    for (int d = 0; d < DD; ++d) {
        float v = m0[d];
        p  += v * f[d];
        sq += v * v;
    }
    ws[4096 + i * DD + n] = p;
    __shared__ float red[DD];
    red[n] = sq;
    __syncthreads();
    for (int o = 64; o > 0; o >>= 1) {
        if (n < o) red[n] += red[n + o];
        __syncthreads();
    }
    if (n == 0) ws[8256 + i] = red[0];
}

__launch_bounds__(1024)
__attribute__((amdgpu_waves_per_eu(4, 4)))
__global__ void k_scan(const float* __restrict__ Am, const float* __restrict__ Bm,
                       const float* __restrict__ Rm, const float* __restrict__ Km,
                       const float* __restrict__ x0, const float* __restrict__ wseq,
                       float* __restrict__ ws) {
    const int tid = threadIdx.x;
    const int r = tid >> 3, s = tid & 7;

    // Thread owns row r, cols {4s+32q+0..3}, q=0..3. 64 matrix VGPRs/thread.
    v2f mK[8], mA[8], mB[8], mR[8];
#pragma unroll
    for (int q = 0; q < 4; ++q) {
        const int col = 4 * s + 32 * q;
        float4 v;
        v = *(const float4*)(Km + r * DD + col);
        mK[2*q] = v2f{v.x, v.y}; mK[2*q+1] = v2f{v.z, v.w};
        v = *(const float4*)(Am + r * DD + col);
        mA[2*q] = v2f{v.x, v.y}; mA[2*q+1] = v2f{v.z, v.w};
        v = *(const float4*)(Bm + r * DD + col);
        mB[2*q] = v2f{v.x, v.y}; mB[2*q+1] = v2f{v.z, v.w};
        v = *(const float4*)(Rm + r * DD + col);
        v.x += Rm[(col + 0) * DD + r];   // Rsym = R + R^T
        v.y += Rm[(col + 1) * DD + r];
        v.z += Rm[(col + 2) * DD + r];
        v.w += Rm[(col + 3) * DD + r];
        mR[2*q] = v2f{v.x, v.y}; mR[2*q+1] = v2f{v.z, v.w};
    }
#pragma unroll
    for (int q = 0; q < 8; ++q) { KEEPV(mK[q]); KEEPV(mA[q]); KEEPV(mB[q]); KEEPV(mR[q]); }

    // Filter state (first 512 threads): filter oi = tid>>4, elems on0..on0+7.
    const int oi = tid >> 4, ol = tid & 15, on0 = ol << 3;
    float y[8], p[8];
    float oa = 1.f, ony2 = 0.f, oyp = 0.f;
    float os4 = 0.f, ofn2 = 0.f, om0 = 0.f, oe = 0.f;

    __shared__ float xs[2][DD];
    __shared__ float us[DD], gs[DD];
    __shared__ float Zl[HH * 131];   // odd stride: conflict-free z-fold reads

    if (tid < 512) {
        os4  = ws[8224 + oi];
        ofn2 = ws[8192 + oi];
        om0  = ws[8256 + oi];
        oe   = ETA_C * os4;
#pragma unroll
        for (int j = 0; j < 8; ++j) {
            y[j] = 0.f;
            p[j] = ws[4096 + oi * DD + on0 + j];
        }
#pragma unroll
        for (int j = 0; j < 8; ++j) Zl[oi * 131 + on0 + j] = os4 * p[j];
    }
    if (tid < DD) {
        float xv = x0[tid];
        xs[0][tid] = xv;
        ws[WSX + tid] = xv;
    }
    __syncthreads();

    float axr = 0.f;
#pragma unroll 1
    for (int t = 0; t < TT; ++t) {
        float* xcur = xs[t & 1];
        float* xnxt = xs[(t & 1) ^ 1];
        float wv = 0.f;
        if (s == 0) wv = wseq[t * DD + r];   // prefetch, consumed in phase B

        // ---- phase A: u[r] = noise[r] - (K x)[r]; (A x)[r] partial kept in reg
        {
            const float4* x4p = (const float4*)xcur;
            v2f aK = v2f{0.f, 0.f}, aA = v2f{0.f, 0.f};
#pragma unroll
            for (int q = 0; q < 4; ++q) {
                float4 xq = x4p[s + 8 * q];
                v2f lo = v2f{xq.x, xq.y}, hi = v2f{xq.z, xq.w};
                aK += mK[2*q] * lo; aK += mK[2*q+1] * hi;
                aA += mA[2*q] * lo; aA += mA[2*q+1] * hi;
            }
            float zp = 0.f;
#pragma unroll
            for (int j = 0; j < 4; ++j) zp += Zl[(4 * s + j) * 131 + r];
            float uval = zp - (aK.x + aK.y);
            float av = aA.x + aA.y;
            uval = dpp_add<0xB1>(uval); uval = dpp_add<0x4E>(uval); uval = dpp_add<0x104>(uval);
            av   = dpp_add<0xB1>(av);   av   = dpp_add<0x4E>(av);   av   = dpp_add<0x104>(av);
            if (s == 0) {
                us[r] = uval;
                ws[WSU + t * DD + r] = uval;   // for deferred cost kernel
            }
            axr = av;
        }
        asm volatile("s_waitcnt lgkmcnt(0)" ::: "memory");
        __builtin_amdgcn_s_barrier();

        // ---- phase B: g = Rsym u ; x_next = Ax + Bu + w
        {
            const float4* u4p = (const float4*)us;
            v2f aR = v2f{0.f, 0.f}, aB = v2f{0.f, 0.f};
#pragma unroll
            for (int q = 0; q < 4; ++q) {
                float4 uq = u4p[s + 8 * q];
                v2f lo = v2f{uq.x, uq.y}, hi = v2f{uq.z, uq.w};
                aR += mR[2*q] * lo; aR += mR[2*q+1] * hi;
                aB += mB[2*q] * lo; aB += mB[2*q+1] * hi;
            }
            float gv = aR.x + aR.y, bv = aB.x + aB.y;
            gv = dpp_add<0xB1>(gv); gv = dpp_add<0x4E>(gv); gv = dpp_add<0x104>(gv);
            bv = dpp_add<0xB1>(bv); bv = dpp_add<0x4E>(bv); bv = dpp_add<0x104>(bv);
            if (s == 0) {
                gs[r] = gv;
                float xn = axr + bv + wv;
                xnxt[r] = xn;
                ws[WSX + (t + 1) * DD + r] = xn;
            }
        }
        asm volatile("s_waitcnt lgkmcnt(0)" ::: "memory");
        __builtin_amdgcn_s_barrier();

        // ---- phase C: filter update with incremental norm tracking (tid<512)
        if (tid < 512) {
            const float4* g4 = (const float4*)(gs + on0);
            float4 ga = g4[0], gb = g4[1];
            float g8[8] = {ga.x, ga.y, ga.z, ga.w, gb.x, gb.y, gb.z, gb.w};
            float yg = 0.f, gp = 0.f, g2 = 0.f;
#pragma unroll
            for (int j = 0; j < 8; ++j) {
                yg += y[j] * g8[j];
                gp += p[j] * g8[j];
                g2 += g8[j] * g8[j];
            }
            yg = dpp_add<0xB1>(yg); yg = dpp_add<0x4E>(yg);
            yg = dpp_add<0x124>(yg); yg = dpp_add<0x128>(yg);
            gp = dpp_add<0xB1>(gp); gp = dpp_add<0x4E>(gp);
            gp = dpp_add<0x124>(gp); gp = dpp_add<0x128>(gp);
            g2 = dpp_add<0xB1>(g2); g2 = dpp_add<0x4E>(g2);
            g2 = dpp_add<0x124>(g2); g2 = dpp_add<0x128>(g2);
            float ny2 = ony2 - 2.f * oe * yg + oe * oe * g2;
            float yp  = oyp - oe * gp;
            float norm2 = oa * oa * om0 + 2.f * oa * yp + ofn2 * ny2;
            float nrm = sqrtf(fmaxf(norm2, 0.f));
            float sc = (nrm > BOUND_C) ? (BOUND_C / nrm) : 1.f;
            oa *= sc; ony2 = ny2 * sc * sc; oyp = yp * sc;
            float ca = os4 * oa, cy = os4 * ofn2;
#pragma unroll
            for (int j = 0; j < 8; ++j) {
                y[j] = sc * (y[j] - oe * g8[j]);
                Zl[oi * 131 + on0 + j] = ca * p[j] + cy * y[j];
            }
        }
        asm volatile("s_waitcnt lgkmcnt(0)" ::: "memory");
        __builtin_amdgcn_s_barrier();
    }
}

// Deferred, fully parallel cost: out[t] = x_t' Q x_t + u_t' R u_t
__launch_bounds__(128)
__global__ void k_cost(const float* __restrict__ Qm, const float* __restrict__ Rm,
                       const float* __restrict__ ws, float* __restrict__ out) {
    const int t = blockIdx.x, r = threadIdx.x;
    __shared__ float xv[DD], uv[DD];
    __shared__ float red[2];
    xv[r] = ws[WSX + t * DD + r];
    uv[r] = ws[WSU + t * DD + r];
    __syncthreads();
    const float4* q4 = (const float4*)(Qm + r * DD);
    const float4* r4 = (const float4*)(Rm + r * DD);
    const float4* x4 = (const float4*)xv;
    const float4* u4 = (const float4*)uv;
    float qa = 0.f, ra = 0.f;
#pragma unroll 8
    for (int j = 0; j < 32; ++j) {
        float4 qv = q4[j], xq = x4[j];
        qa += qv.x*xq.x + qv.y*xq.y + qv.z*xq.z + qv.w*xq.w;
        float4 rv = r4[j], uq = u4[j];
        ra += rv.x*uq.x + rv.y*uq.y + rv.z*uq.z + rv.w*uq.w;
    }
    float part = xv[r] * qa + uv[r] * ra;
    part = dpp_add<0xB1>(part); part = dpp_add<0x4E>(part);
    part = dpp_add<0x124>(part); part = dpp_add<0x128>(part);
    part += __shfl_xor(part, 16); part += __shfl_xor(part, 32);
    if ((r & 63) == 0) red[r >> 6] = part;
    __syncthreads();
    if (r == 0) out[t] = red[0] + red[1];
}

extern "C" void kernel_launch(void* const* d_in, const int* in_sizes, int n_in,
                              void* d_out, int out_size, void* d_ws, size_t ws_size,
                              hipStream_t stream) {
    const float* A     = (const float*)d_in[0];
    const float* B     = (const float*)d_in[1];
    const float* Q     = (const float*)d_in[2];
    const float* R     = (const float*)d_in[3];
    const float* K     = (const float*)d_in[4];
    const float* sigma = (const float*)d_in[5];
    const float* phi   = (const float*)d_in[6];
    const float* M0    = (const float*)d_in[7];
    const float* x0    = (const float*)d_in[8];
    const float* Whist = (const float*)d_in[9];
    const float* wseq  = (const float*)d_in[10];
    float* out = (float*)d_out;
    float* ws  = (float*)d_ws;

    hipLaunchKernelGGL(k_precompF, dim3(HH), dim3(DD), 0, stream, Whist, phi, sigma, ws);
    hipLaunchKernelGGL(k_precompP, dim3(HH), dim3(DD), 0, stream, M0, ws);
    hipLaunchKernelGGL(k_scan, dim3(1), dim3(1024), 0, stream,
                       A, B, R, K, x0, wseq, ws);
    hipLaunchKernelGGL(k_cost, dim3(TT), dim3(DD), 0, stream, Q, R, ws, out);
}

// Round 10
// 428.023 us; speedup vs baseline: 1.0150x; 1.0131x over previous
//
#include <hip/hip_runtime.h>
#include <math.h>

#define DD 128
#define HH 32
#define MH 64
#define TT 256
#define ETA_C 1e-3f
#define BOUND_C 1.4907119849998598f   // sqrt(2/0.9)

// ws float layout:
//   F[32][128] @ 0     fn2[32] @ 8192   s4[32] @ 8224   m0n2[32] @ 8256
//   P[32][128] @ 4096
//   X store @ 8320 (257*128)   U store @ 41216 (256*128)
//   Rsym    @ 73984 (128*128)
#define WSX 8320
#define WSU 41216
#define WSR 73984

// dynamic LDS layout (floats):
//   Ksm @ 0 (16384), Rsm @ 16384 (16384), xs0 @ 32768, xs1 @ 32896,
//   us @ 33024, gs @ 33152, Zl @ 33280 (32*131=4192)  -> total 37472 floats
#define LDS_FLOATS 37472
#define LDS_BYTES  (LDS_FLOATS * 4)

typedef float v2f __attribute__((ext_vector_type(2)));

#define KEEPV(v) asm volatile("" : "+v"(v))

template <int CTRL>
__device__ __forceinline__ float dpp_add(float x) {
    int y = __builtin_amdgcn_update_dpp(0, __float_as_int(x), CTRL, 0xF, 0xF, true);
    return x + __int_as_float(y);
}
// 0xB1 quad xor1, 0x4E quad xor2, 0x104 row_shl:4 (lane i <- lane i+4),
// 0x124 row_ror:4, 0x128 row_ror:8

__global__ void k_precompF(const float* __restrict__ W, const float* __restrict__ phi,
                           const float* __restrict__ sigma, float* __restrict__ ws) {
    int i = blockIdx.x, d = threadIdx.x;
    float acc = 0.f;
#pragma unroll
    for (int m = 0; m < MH; ++m) acc += W[d * MH + m] * phi[m * HH + i];
    ws[i * DD + d] = acc;
    __shared__ float red[DD];
    red[d] = acc * acc;
    __syncthreads();
    for (int o = 64; o > 0; o >>= 1) {
        if (d < o) red[d] += red[d + o];
        __syncthreads();
    }
    if (d == 0) {
        ws[8192 + i] = red[0];
        ws[8224 + i] = sqrtf(sqrtf(sigma[i]));
    }
}

__global__ void k_precompP(const float* __restrict__ M0, float* __restrict__ ws) {
    int i = blockIdx.x, n = threadIdx.x;
    const float* f  = ws + i * DD;
    const float* m0 = M0 + i * DD * DD + n * DD;
    float p = 0.f, sq = 0.f;
#pragma unroll 4
    for (int d = 0; d < DD; ++d) {
        float v = m0[d];
        p  += v * f[d];
        sq += v * v;
    }
    ws[4096 + i * DD + n] = p;
    __shared__ float red[DD];
    red[n] = sq;
    __syncthreads();
    for (int o = 64; o > 0; o >>= 1) {
        if (n < o) red[n] += red[n + o];
        __syncthreads();
    }
    if (n == 0) ws[8256 + i] = red[0];
}

// Rsym = R + R^T, fully parallel
__global__ void k_precompR(const float* __restrict__ Rm, float* __restrict__ ws) {
    int i = blockIdx.x, j = threadIdx.x;
    ws[WSR + i * DD + j] = Rm[i * DD + j] + Rm[j * DD + i];
}

__launch_bounds__(1024)
__global__ void k_scan(const float* __restrict__ Am, const float* __restrict__ Bm,
                       const float* __restrict__ Km, const float* __restrict__ x0,
                       const float* __restrict__ wseq, float* __restrict__ ws) {
    extern __shared__ float lds[];
    float* Ksm = lds;
    float* Rsm = lds + 16384;
    float* xs0 = lds + 32768;
    float* xs1 = lds + 32896;
    float* us  = lds + 33024;
    float* gs  = lds + 33152;
    float* Zl  = lds + 33280;   // stride-131 rows

    const int tid = threadIdx.x;
    const int r = tid >> 3, s = tid & 7;

    // Stage K and Rsym into LDS (coalesced, one-time).
    {
        const float4* ksrc = (const float4*)Km;
        const float4* rsrc = (const float4*)(ws + WSR);
        float4* kd = (float4*)Ksm;
        float4* rd = (float4*)Rsm;
#pragma unroll
        for (int q = 0; q < 4; ++q) {
            kd[tid + 1024 * q] = ksrc[tid + 1024 * q];
            rd[tid + 1024 * q] = rsrc[tid + 1024 * q];
        }
    }

    // Register-resident A, B: thread owns row r, cols {4s+32q+0..3}, q=0..3.
    v2f mA[8], mB[8];
#pragma unroll
    for (int q = 0; q < 4; ++q) {
        const int col = 4 * s + 32 * q;
        float4 v;
        v = *(const float4*)(Am + r * DD + col);
        mA[2*q] = v2f{v.x, v.y}; mA[2*q+1] = v2f{v.z, v.w};
        v = *(const float4*)(Bm + r * DD + col);
        mB[2*q] = v2f{v.x, v.y}; mB[2*q+1] = v2f{v.z, v.w};
    }
#pragma unroll
    for (int q = 0; q < 8; ++q) { KEEPV(mA[q]); KEEPV(mB[q]); }

    // Filter state (first 512 threads): filter oi = tid>>4, elems on0..on0+7.
    const int oi = tid >> 4, ol = tid & 15, on0 = ol << 3;
    float y[8], p[8];
    float oa = 1.f, ony2 = 0.f, oyp = 0.f;
    float os4 = 0.f, ofn2 = 0.f, om0 = 0.f, oe = 0.f;

    if (tid < 512) {
        os4  = ws[8224 + oi];
        ofn2 = ws[8192 + oi];
        om0  = ws[8256 + oi];
        oe   = ETA_C * os4;
#pragma unroll
        for (int j = 0; j < 8; ++j) {
            y[j] = 0.f;
            p[j] = ws[4096 + oi * DD + on0 + j];
        }
#pragma unroll
        for (int j = 0; j < 8; ++j) Zl[oi * 131 + on0 + j] = os4 * p[j];
    }
    if (tid < DD) {
        float xv = x0[tid];
        xs0[tid] = xv;
        ws[WSX + tid] = xv;
    }
    __syncthreads();

    float axr = 0.f;
#pragma unroll 1
    for (int t = 0; t < TT; ++t) {
        float* xcur = (t & 1) ? xs1 : xs0;
        float* xnxt = (t & 1) ? xs0 : xs1;
        float wv = 0.f;
        if (s == 0) wv = wseq[t * DD + r];   // prefetch, consumed in phase B

        // ---- phase A: u[r] = noise[r] - (K x)[r]; (A x)[r] partial kept in reg
        {
            const float4* x4p  = (const float4*)xcur;
            const float4* krow = (const float4*)(Ksm + r * DD);
            float aK = 0.f;
            v2f aA = v2f{0.f, 0.f};
#pragma unroll
            for (int q = 0; q < 4; ++q) {
                float4 xq = x4p[s + 8 * q];
                float4 kq = krow[s + 8 * q];
                aK += kq.x * xq.x + kq.y * xq.y + kq.z * xq.z + kq.w * xq.w;
                v2f lo = v2f{xq.x, xq.y}, hi = v2f{xq.z, xq.w};
                aA += mA[2*q] * lo; aA += mA[2*q+1] * hi;
            }
            float zp = 0.f;
#pragma unroll
            for (int j = 0; j < 4; ++j) zp += Zl[(4 * s + j) * 131 + r];
            float uval = zp - aK;
            float av = aA.x + aA.y;
            uval = dpp_add<0xB1>(uval); uval = dpp_add<0x4E>(uval); uval = dpp_add<0x104>(uval);
            av   = dpp_add<0xB1>(av);   av   = dpp_add<0x4E>(av);   av   = dpp_add<0x104>(av);
            if (s == 0) {
                us[r] = uval;
                ws[WSU + t * DD + r] = uval;   // for deferred cost kernel
            }
            axr = av;
        }
        asm volatile("s_waitcnt lgkmcnt(0)" ::: "memory");
        __builtin_amdgcn_s_barrier();

        // ---- phase B: g = Rsym u ; x_next = Ax + Bu + w
        {
            const float4* u4p  = (const float4*)us;
            const float4* rrow = (const float4*)(Rsm + r * DD);
            float gR = 0.f;
            v2f aB = v2f{0.f, 0.f};
#pragma unroll
            for (int q = 0; q < 4; ++q) {
                float4 uq = u4p[s + 8 * q];
                float4 rq = rrow[s + 8 * q];
                gR += rq.x * uq.x + rq.y * uq.y + rq.z * uq.z + rq.w * uq.w;
                v2f lo = v2f{uq.x, uq.y}, hi = v2f{uq.z, uq.w};
                aB += mB[2*q] * lo; aB += mB[2*q+1] * hi;
            }
            float bv = aB.x + aB.y;
            gR = dpp_add<0xB1>(gR); gR = dpp_add<0x4E>(gR); gR = dpp_add<0x104>(gR);
            bv = dpp_add<0xB1>(bv); bv = dpp_add<0x4E>(bv); bv = dpp_add<0x104>(bv);
            if (s == 0) {
                gs[r] = gR;
                float xn = axr + bv + wv;
                xnxt[r] = xn;
                ws[WSX + (t + 1) * DD + r] = xn;
            }
        }
        asm volatile("s_waitcnt lgkmcnt(0)" ::: "memory");
        __builtin_amdgcn_s_barrier();

        // ---- phase C: filter update with incremental norm tracking (tid<512)
        if (tid < 512) {
            const float4* g4 = (const float4*)(gs + on0);
            float4 ga = g4[0], gb = g4[1];
            float g8[8] = {ga.x, ga.y, ga.z, ga.w, gb.x, gb.y, gb.z, gb.w};
            float yg = 0.f, gp = 0.f, g2 = 0.f;
#pragma unroll
            for (int j = 0; j < 8; ++j) {
                yg += y[j] * g8[j];
                gp += p[j] * g8[j];
                g2 += g8[j] * g8[j];
            }
            yg = dpp_add<0xB1>(yg); yg = dpp_add<0x4E>(yg);
            yg = dpp_add<0x124>(yg); yg = dpp_add<0x128>(yg);
            gp = dpp_add<0xB1>(gp); gp = dpp_add<0x4E>(gp);
            gp = dpp_add<0x124>(gp); gp = dpp_add<0x128>(gp);
            g2 = dpp_add<0xB1>(g2); g2 = dpp_add<0x4E>(g2);
            g2 = dpp_add<0x124>(g2); g2 = dpp_add<0x128>(g2);
            float ny2 = ony2 - 2.f * oe * yg + oe * oe * g2;
            float yp  = oyp - oe * gp;
            float norm2 = oa * oa * om0 + 2.f * oa * yp + ofn2 * ny2;
            float nrm = sqrtf(fmaxf(norm2, 0.f));
            float sc = (nrm > BOUND_C) ? (BOUND_C / nrm) : 1.f;
            oa *= sc; ony2 = ny2 * sc * sc; oyp = yp * sc;
            float ca = os4 * oa, cy = os4 * ofn2;
#pragma unroll
            for (int j = 0; j < 8; ++j) {
                y[j] = sc * (y[j] - oe * g8[j]);
                Zl[oi * 131 + on0 + j] = ca * p[j] + cy * y[j];
            }
        }
        asm volatile("s_waitcnt lgkmcnt(0)" ::: "memory");
        __builtin_amdgcn_s_barrier();
    }
}

// Deferred, fully parallel cost: out[t] = x_t' Q x_t + u_t' R u_t
__launch_bounds__(128)
__global__ void k_cost(const float* __restrict__ Qm, const float* __restrict__ Rm,
                       const float* __restrict__ ws, float* __restrict__ out) {
    const int t = blockIdx.x, r = threadIdx.x;
    __shared__ float xv[DD], uv[DD];
    __shared__ float red[2];
    xv[r] = ws[WSX + t * DD + r];
    uv[r] = ws[WSU + t * DD + r];
    __syncthreads();
    const float4* q4 = (const float4*)(Qm + r * DD);
    const float4* r4 = (const float4*)(Rm + r * DD);
    const float4* x4 = (const float4*)xv;
    const float4* u4 = (const float4*)uv;
    float qa = 0.f, ra = 0.f;
#pragma unroll 8
    for (int j = 0; j < 32; ++j) {
        float4 qv = q4[j], xq = x4[j];
        qa += qv.x*xq.x + qv.y*xq.y + qv.z*xq.z + qv.w*xq.w;
        float4 rv = r4[j], uq = u4[j];
        ra += rv.x*uq.x + rv.y*uq.y + rv.z*uq.z + rv.w*uq.w;
    }
    float part = xv[r] * qa + uv[r] * ra;
    part = dpp_add<0xB1>(part); part = dpp_add<0x4E>(part);
    part = dpp_add<0x124>(part); part = dpp_add<0x128>(part);
    part += __shfl_xor(part, 16); part += __shfl_xor(part, 32);
    if ((r & 63) == 0) red[r >> 6] = part;
    __syncthreads();
    if (r == 0) out[t] = red[0] + red[1];
}

extern "C" void kernel_launch(void* const* d_in, const int* in_sizes, int n_in,
                              void* d_out, int out_size, void* d_ws, size_t ws_size,
                              hipStream_t stream) {
    const float* A     = (const float*)d_in[0];
    const float* B     = (const float*)d_in[1];
    const float* Q     = (const float*)d_in[2];
    const float* R     = (const float*)d_in[3];
    const float* K     = (const float*)d_in[4];
    const float* sigma = (const float*)d_in[5];
    const float* phi   = (const float*)d_in[6];
    const float* M0    = (const float*)d_in[7];
    const float* x0    = (const float*)d_in[8];
    const float* Whist = (const float*)d_in[9];
    const float* wseq  = (const float*)d_in[10];
    float* out = (float*)d_out;
    float* ws  = (float*)d_ws;

    // allow >64KB dynamic LDS for k_scan (idempotent; not a stream op, capture-safe)
    (void)hipFuncSetAttribute(reinterpret_cast<const void*>(&k_scan),
                              hipFuncAttributeMaxDynamicSharedMemorySize, LDS_BYTES);

    hipLaunchKernelGGL(k_precompF, dim3(HH), dim3(DD), 0, stream, Whist, phi, sigma, ws);
    hipLaunchKernelGGL(k_precompP, dim3(HH), dim3(DD), 0, stream, M0, ws);
    hipLaunchKernelGGL(k_precompR, dim3(DD), dim3(DD), 0, stream, R, ws);
    hipLaunchKernelGGL(k_scan, dim3(1), dim3(1024), LDS_BYTES, stream,
                       A, B, K, x0, wseq, ws);
    hipLaunchKernelGGL(k_cost, dim3(TT), dim3(DD), 0, stream, Q, R, ws, out);
}